// Round 4
// baseline (478.940 us; speedup 1.0000x reference)
//
#include <hip/hip_runtime.h>
#include <hip/hip_bf16.h>
#include <cstdint>
#include <cstddef>

#define LSEQ 768
#define CS 384
#define CZ 128
#define NH 8
#define HD 48
#define LL (LSEQ*LSEQ)   /* 589824 */
#define WELEM 147456     /* 384*384 */

static constexpr float EPS = 1e-5f;
static constexpr float QK_SCALE = 0.14433756729740643f; /* 1/sqrt(48) */

typedef unsigned short u16;
typedef __attribute__((ext_vector_type(8))) short bf16x8;
typedef __attribute__((ext_vector_type(4))) float f32x4;

__device__ __forceinline__ u16 f2bf_s(float f){
  unsigned int u = __float_as_uint(f);
  unsigned int r = u + 0x7fffu + ((u >> 16) & 1u);  /* RNE */
  return (u16)(r >> 16);
}

/* ------- 1. fused mega-kernel:
     blocks 0..287      = MFMA GEMM LN(single) @ {Wq,Wk,Wv,Wg}^T
                          (LN computed per-block into LDS, W cast f32->bf16 inline)
     blocks 288..431    = cast Wo fp32->bf16 (for k_final)
     blocks 432..3503   = LayerNorm(pair) + z@Wb -> bias[h][i][j]
   qkvg + cast work (~15us) hides under the BW-bound pair path (~50us). ------- */
#define NQKVG 288
#define NCAST 144
#define NPAIR 3072
__global__ __launch_bounds__(256,4) void k_pair_qkvg(
    const float* __restrict__ pair,
    const float* __restrict__ g_z,
    const float* __restrict__ b_z,
    const float* __restrict__ Wb,
    float* __restrict__ bias,
    const float* __restrict__ single,
    const float* __restrict__ g_s,
    const float* __restrict__ b_s,
    const float* __restrict__ Wq, const float* __restrict__ Wk,
    const float* __restrict__ Wv, const float* __restrict__ Wg,
    const float* __restrict__ Wo,
    const float* __restrict__ bg,
    u16* __restrict__ Wbf_o,
    u16* __restrict__ qb, u16* __restrict__ kb,
    u16* __restrict__ vT, float* __restrict__ gate){
  const int t = threadIdx.x;
  const int lane = t & 63;

  __shared__ u16 lds_s[64][384];   /* LN(single) tile, 48 KB; qkvg path only */

  if(blockIdx.x < NQKVG){
    /* ---- qkvg path: bx = blk%12 (m-tile), by = blk/12 (which*6+ntile) ---- */
    const int blk = blockIdx.x;
    const int w = t >> 6, ln = lane & 15, quad = lane >> 4;
    const int bx = blk % 12, by = blk / 12;
    const int m0 = bx*64 + w*16;
    const int which = by / 6;
    const int n0 = (by % 6)*64;
    const float* Wf = (which==0)?Wq:(which==1)?Wk:(which==2)?Wv:Wg;

    /* LN(single) for this wave's 16 rows -> LDS (wave-local: no barrier).
       Bit-identical to the old k_prep path (same ops, same order). */
#pragma unroll 1
    for(int rr=0; rr<16; rr++){
      const int gi = m0 + rr;
      const float* row = single + (size_t)gi*CS;
      float x[6];
      float sum = 0.f;
#pragma unroll
      for(int e=0;e<6;e++){ x[e] = row[lane + 64*e]; sum += x[e]; }
#pragma unroll
      for(int m=32;m>=1;m>>=1) sum += __shfl_xor(sum, m, 64);
      const float mu = sum * (1.f/CS);
      float vs = 0.f;
#pragma unroll
      for(int e=0;e<6;e++){ float d = x[e]-mu; vs += d*d; }
#pragma unroll
      for(int m=32;m>=1;m>>=1) vs += __shfl_xor(vs, m, 64);
      const float rs = rsqrtf(vs*(1.f/CS) + EPS);
#pragma unroll
      for(int e=0;e<6;e++){
        int c = lane + 64*e;
        lds_s[w*16 + rr][c] = f2bf_s((x[e]-mu)*rs*g_s[c] + b_s[c]);
      }
    }

    const u16* arow = &lds_s[w*16 + ln][quad*8];
    const float* browf = Wf + (size_t)(n0+ln)*CS + quad*8;

    f32x4 acc[4];
#pragma unroll
    for(int nb=0;nb<4;nb++) acc[nb] = (f32x4){0.f,0.f,0.f,0.f};

#pragma unroll 2
    for(int k0=0;k0<CS;k0+=32){
      bf16x8 a = *(const bf16x8*)(arow + k0);
#pragma unroll
      for(int nb=0;nb<4;nb++){
        const float* bp = browf + (size_t)nb*16*CS + k0;
        const float4 u0 = *(const float4*)(bp);
        const float4 u1 = *(const float4*)(bp + 4);
        bf16x8 bb;
        bb[0] = (short)f2bf_s(u0.x); bb[1] = (short)f2bf_s(u0.y);
        bb[2] = (short)f2bf_s(u0.z); bb[3] = (short)f2bf_s(u0.w);
        bb[4] = (short)f2bf_s(u1.x); bb[5] = (short)f2bf_s(u1.y);
        bb[6] = (short)f2bf_s(u1.z); bb[7] = (short)f2bf_s(u1.w);
        acc[nb] = __builtin_amdgcn_mfma_f32_16x16x32_bf16(a, bb, acc[nb], 0,0,0);
      }
    }

    if(which == 2){           /* v -> transposed bf16, 8B stores */
#pragma unroll
      for(int nb=0;nb<4;nb++){
        const int col = n0 + nb*16 + ln;
        ushort4 sv;
        sv.x = f2bf_s(acc[nb][0]); sv.y = f2bf_s(acc[nb][1]);
        sv.z = f2bf_s(acc[nb][2]); sv.w = f2bf_s(acc[nb][3]);
        *(ushort4*)(vT + (size_t)col*LSEQ + m0 + quad*4) = sv;
      }
    } else {
#pragma unroll
      for(int nb=0;nb<4;nb++){
#pragma unroll
        for(int r=0;r<4;r++){
          const int row = m0 + quad*4 + r;
          const int col = n0 + nb*16 + ln;
          const float val = acc[nb][r];
          if(which==0)      qb[row*CS+col] = f2bf_s(val*QK_SCALE);
          else if(which==1) kb[row*CS+col] = f2bf_s(val);
          else              gate[row*CS+col] = 1.f/(1.f + __expf(-(val + bg[col])));
        }
      }
    }
    return;
  }

  if(blockIdx.x < NQKVG + NCAST){
    /* ---- Wo cast path: 144 blocks x 256 threads x float4 = 147456 elems ---- */
    const int idx = (blockIdx.x - NQKVG)*256 + t;   /* < 36864 */
    const int off = idx*4;
    const float4 u = *(const float4*)(Wo + off);
    ushort4 o;
    o.x = f2bf_s(u.x); o.y = f2bf_s(u.y); o.z = f2bf_s(u.z); o.w = f2bf_s(u.w);
    *(ushort4*)(Wbf_o + off) = o;
    return;
  }

  /* ---- pair_bias path (unchanged body) ---- */
  const int wave = t >> 6;
  const int sub  = lane >> 4;
  const int lg   = lane & 15;
  const int z0   = lg*8;

  float wb_r[64], gz[8], bz[8];
#pragma unroll
  for(int zz=0; zz<8; zz++){
    gz[zz] = g_z[z0+zz];
    bz[zz] = b_z[z0+zz];
#pragma unroll
    for(int h=0; h<NH; h++) wb_r[zz*8+h] = Wb[(z0+zz)*NH + h];
  }
  const int hmap = 4*(lg&1) + (lg&2) + ((lg>>2)&1);

  const int ngroups = LL/16;
  for(int gidx = blockIdx.x - (NQKVG+NCAST); gidx < ngroups; gidx += NPAIR){
    const int r = gidx*16 + wave*4 + sub;
    const float4 u0 = *(const float4*)(pair + (size_t)r*CZ + z0);
    const float4 u1 = *(const float4*)(pair + (size_t)r*CZ + z0 + 4);
    float x[8] = {u0.x,u0.y,u0.z,u0.w,u1.x,u1.y,u1.z,u1.w};
    float sum=0.f, sq=0.f;
#pragma unroll
    for(int e=0;e<8;e++){ sum += x[e]; sq += x[e]*x[e]; }
#pragma unroll
    for(int m=1;m<16;m<<=1){ sum += __shfl_xor(sum,m,64); sq += __shfl_xor(sq,m,64); }
    const float mu = sum*(1.f/CZ);
    const float rs = rsqrtf(sq*(1.f/CZ) - mu*mu + EPS);
    float acc[8];
#pragma unroll
    for(int h=0;h<8;h++) acc[h]=0.f;
#pragma unroll
    for(int e=0;e<8;e++){
      const float zn = (x[e]-mu)*rs*gz[e] + bz[e];
#pragma unroll
      for(int h=0;h<8;h++) acc[h] += zn*wb_r[e*8+h];
    }
    float k1[4];
    {
      const bool hi = lg & 1;
#pragma unroll
      for(int j=0;j<4;j++){
        float send = hi ? acc[j] : acc[j+4];
        float recv = __shfl_xor(send, 1, 64);
        k1[j] = (hi ? acc[j+4] : acc[j]) + recv;
      }
    }
    float k2[2];
    {
      const bool hi = lg & 2;
#pragma unroll
      for(int j=0;j<2;j++){
        float send = hi ? k1[j] : k1[j+2];
        float recv = __shfl_xor(send, 2, 64);
        k2[j] = (hi ? k1[j+2] : k1[j]) + recv;
      }
    }
    float k3;
    {
      const bool hi = lg & 4;
      float send = hi ? k2[0] : k2[1];
      float recv = __shfl_xor(send, 4, 64);
      k3 = (hi ? k2[1] : k2[0]) + recv;
    }
    k3 += __shfl_xor(k3, 8, 64);
    if(lg < 8) bias[(size_t)hmap*LL + r] = k3;
  }
}

/* ---------- 2. fused flash attention (bf16 frags via vector loads) ---------- */
__global__ __launch_bounds__(256) void k_flash(
    const u16* __restrict__ qb, const u16* __restrict__ kb,
    const u16* __restrict__ vT, const float* __restrict__ bias,
    u16* __restrict__ attno_bf){
  const int h  = blockIdx.y;
  const int i0 = blockIdx.x * 16;
  const int t  = threadIdx.x;
  const int w    = t >> 6;
  const int lane = t & 63;
  const int ln   = lane & 15;
  const int quad = lane >> 4;

  __shared__ u16  S_lds[4][16][32];
  __shared__ float O_lds[4][16][48];
  __shared__ float ml_lds[4][2][16];

  const bf16x8 zf = {0,0,0,0,0,0,0,0};

  bf16x8 aq0, aq1;
  {
    const u16* qrow = qb + (size_t)(i0 + ln)*CS + h*HD;
    aq0 = *(const bf16x8*)(qrow + quad*8);
    aq1 = (quad < 2) ? *(const bf16x8*)(qrow + 32 + quad*8) : zf;
  }

  float m_r[4], l_r[4];
  f32x4 o[3];
#pragma unroll
  for(int r=0;r<4;r++){ m_r[r] = -INFINITY; l_r[r] = 0.f; }
#pragma unroll
  for(int db=0;db<3;db++) o[db] = (f32x4){0.f,0.f,0.f,0.f};

  for(int jt=0; jt<6; jt++){
    const int j0 = w*192 + jt*32;
    f32x4 s_f[2];
#pragma unroll
    for(int jb=0;jb<2;jb++){
      const u16* krow = kb + (size_t)(j0 + jb*16 + ln)*CS + h*HD;
      bf16x8 bk0 = *(const bf16x8*)(krow + quad*8);
      bf16x8 bk1 = (quad < 2) ? *(const bf16x8*)(krow + 32 + quad*8) : zf;
      f32x4 acc = (f32x4){0.f,0.f,0.f,0.f};
      acc = __builtin_amdgcn_mfma_f32_16x16x32_bf16(aq0, bk0, acc, 0,0,0);
      acc = __builtin_amdgcn_mfma_f32_16x16x32_bf16(aq1, bk1, acc, 0,0,0);
      s_f[jb] = acc;
    }
    float sv[2][4];
#pragma unroll
    for(int jb=0;jb<2;jb++)
#pragma unroll
      for(int r=0;r<4;r++)
        sv[jb][r] = s_f[jb][r] +
          bias[(size_t)h*LL + (size_t)(i0 + quad*4 + r)*LSEQ + j0 + jb*16 + ln];
    float tmax[4];
#pragma unroll
    for(int r=0;r<4;r++) tmax[r] = fmaxf(sv[0][r], sv[1][r]);
#pragma unroll
    for(int r=0;r<4;r++)
#pragma unroll
      for(int m=1;m<16;m<<=1) tmax[r] = fmaxf(tmax[r], __shfl_xor(tmax[r], m, 64));
    float alpha[4];
#pragma unroll
    for(int r=0;r<4;r++){
      const float mn = fmaxf(m_r[r], tmax[r]);
      alpha[r] = __expf(m_r[r] - mn);
      m_r[r] = mn;
    }
    float p[2][4], tsum[4];
#pragma unroll
    for(int r=0;r<4;r++){
      p[0][r] = __expf(sv[0][r] - m_r[r]);
      p[1][r] = __expf(sv[1][r] - m_r[r]);
      tsum[r] = p[0][r] + p[1][r];
    }
#pragma unroll
    for(int r=0;r<4;r++)
#pragma unroll
      for(int m=1;m<16;m<<=1) tsum[r] += __shfl_xor(tsum[r], m, 64);
#pragma unroll
    for(int r=0;r<4;r++) l_r[r] = l_r[r]*alpha[r] + tsum[r];
#pragma unroll
    for(int db=0;db<3;db++)
#pragma unroll
      for(int r=0;r<4;r++) o[db][r] *= alpha[r];
#pragma unroll
    for(int jb=0;jb<2;jb++)
#pragma unroll
      for(int r=0;r<4;r++) S_lds[w][quad*4+r][jb*16+ln] = f2bf_s(p[jb][r]);
    bf16x8 ap = *(const bf16x8*)&S_lds[w][ln][quad*8];
#pragma unroll
    for(int db=0;db<3;db++){
      bf16x8 bv = *(const bf16x8*)(vT + (size_t)(h*HD + db*16 + ln)*LSEQ + j0 + quad*8);
      o[db] = __builtin_amdgcn_mfma_f32_16x16x32_bf16(ap, bv, o[db], 0,0,0);
    }
  }

#pragma unroll
  for(int db=0;db<3;db++)
#pragma unroll
    for(int r=0;r<4;r++) O_lds[w][quad*4+r][db*16+ln] = o[db][r];
  if(ln == 0){
#pragma unroll
    for(int r=0;r<4;r++){
      ml_lds[w][0][quad*4+r] = m_r[r];
      ml_lds[w][1][quad*4+r] = l_r[r];
    }
  }
  __syncthreads();
#pragma unroll
  for(int e=0;e<3;e++){
    const int idx = t + e*256;
    const int row = idx / 48, d = idx % 48;
    float M = ml_lds[0][0][row];
#pragma unroll
    for(int ww=1;ww<4;ww++) M = fmaxf(M, ml_lds[ww][0][row]);
    float L = 0.f, O = 0.f;
#pragma unroll
    for(int ww=0;ww<4;ww++){
      const float f = __expf(ml_lds[ww][0][row] - M);
      L += ml_lds[ww][1][row] * f;
      O += O_lds[ww][row][d] * f;
    }
    attno_bf[(size_t)(i0+row)*CS + h*HD + d] = f2bf_s(O / L);
  }
}

/* ---- 3. MFMA GEMM: out = single + gate * (attno_bf @ Wo^T + bo) ---- */
__global__ __launch_bounds__(256) void k_final(
    const u16* __restrict__ attno_bf, const u16* __restrict__ Wo_bf,
    const float* __restrict__ bo, const float* __restrict__ single,
    const float* __restrict__ gate, float* __restrict__ out){
  const int t = threadIdx.x;
  const int w = t >> 6, lane = t & 63, ln = lane & 15, quad = lane >> 4;
  const int m0 = blockIdx.x*64 + w*16;
  const int n0 = blockIdx.y*64;

  const u16* arow = attno_bf + (size_t)(m0+ln)*CS + quad*8;
  const u16* brow = Wo_bf + (size_t)(n0+ln)*CS + quad*8;

  f32x4 acc[4];
#pragma unroll
  for(int nb=0;nb<4;nb++) acc[nb] = (f32x4){0.f,0.f,0.f,0.f};

#pragma unroll 4
  for(int k0=0;k0<CS;k0+=32){
    bf16x8 a = *(const bf16x8*)(arow + k0);
#pragma unroll
    for(int nb=0;nb<4;nb++){
      bf16x8 bb = *(const bf16x8*)(brow + (size_t)nb*16*CS + k0);
      acc[nb] = __builtin_amdgcn_mfma_f32_16x16x32_bf16(a, bb, acc[nb], 0,0,0);
    }
  }
#pragma unroll
  for(int nb=0;nb<4;nb++){
#pragma unroll
    for(int r=0;r<4;r++){
      const int row = m0 + quad*4 + r;
      const int col = n0 + nb*16 + ln;
      const float val = acc[nb][r] + bo[col];
      out[row*CS+col] = single[row*CS+col] + gate[row*CS+col]*val;
    }
  }
}

extern "C" void kernel_launch(void* const* d_in, const int* in_sizes, int n_in,
                              void* d_out, int out_size, void* d_ws, size_t ws_size,
                              hipStream_t stream){
  (void)in_sizes; (void)n_in; (void)out_size; (void)ws_size;
  const float* single = (const float*)d_in[0];
  const float* pair   = (const float*)d_in[1];
  const float* g_s    = (const float*)d_in[2];
  const float* b_s    = (const float*)d_in[3];
  const float* g_z    = (const float*)d_in[4];
  const float* b_z    = (const float*)d_in[5];
  const float* Wq     = (const float*)d_in[6];
  const float* Wk     = (const float*)d_in[7];
  const float* Wv     = (const float*)d_in[8];
  const float* Wb     = (const float*)d_in[9];
  const float* Wo     = (const float*)d_in[10];
  const float* bo     = (const float*)d_in[11];
  const float* Wg     = (const float*)d_in[12];
  const float* bg     = (const float*)d_in[13];
  float* out = (float*)d_out;

  float* ws     = (float*)d_ws;
  float* bias   = ws;                       /* [8][768][768] f32 */
  float* gate   = ws + 4718592;             /* [768][384] f32    */
  u16*   s_bf   = (u16*)(gate + 294912);    /* (unused now)      */
  u16*   qb     = s_bf + 294912;            /* [768][384] bf16   */
  u16*   kb     = qb + 294912;              /* [768][384] bf16   */
  u16*   vT     = kb + 294912;              /* [384][768] bf16   */
  u16*   attno  = vT + 294912;              /* [768][384] bf16   */
  u16*   Wbf    = attno + 294912;           /* slot 4 = Wo bf16  */
  u16*   Wbf_o  = Wbf + (size_t)4*WELEM;

  hipLaunchKernelGGL(k_pair_qkvg, dim3(NQKVG+NCAST+NPAIR), dim3(256), 0, stream,
                     pair, g_z, b_z, Wb, bias,
                     single, g_s, b_s, Wq, Wk, Wv, Wg, Wo, bg,
                     Wbf_o, qb, kb, vT, gate);
  hipLaunchKernelGGL(k_flash,     dim3(48,8),       dim3(256), 0, stream, qb, kb, vT, bias, attno);
  hipLaunchKernelGGL(k_final,     dim3(12,6),       dim3(256), 0, stream,
                     attno, Wbf_o, bo, single, gate, out);
}

// Round 5
// 476.668 us; speedup vs baseline: 1.0048x; 1.0048x over previous
//
#include <hip/hip_runtime.h>
#include <hip/hip_bf16.h>
#include <cstdint>
#include <cstddef>

#define LSEQ 768
#define CS 384
#define CZ 128
#define NH 8
#define HD 48
#define LL (LSEQ*LSEQ)   /* 589824 */
#define WELEM 147456     /* 384*384 */

static constexpr float EPS = 1e-5f;
static constexpr float QK_SCALE = 0.14433756729740643f; /* 1/sqrt(48) */

typedef unsigned short u16;
typedef __attribute__((ext_vector_type(8))) short bf16x8;
typedef __attribute__((ext_vector_type(4))) float f32x4;

__device__ __forceinline__ u16 f2bf_s(float f){
  unsigned int u = __float_as_uint(f);
  unsigned int r = u + 0x7fffu + ((u >> 16) & 1u);  /* RNE */
  return (u16)(r >> 16);
}

/* ------- 1. fused mega-kernel:
     blocks 0..383      = MFMA GEMM LN(single) @ {Wq,Wk,Wv,Wg}^T
                          (48-row m-tile, 3 active waves, LDS 36KB -> 4 blocks/CU)
     blocks 384..527    = cast Wo fp32->bf16 (for k_final)
     blocks 528..3599   = LayerNorm(pair) + z@Wb -> bias[h][i][j]
   qkvg + cast work hides under the BW-bound pair path (~50us); 36KB LDS
   keeps the pair path at 4 blocks/CU (4 waves/SIMD) for load-latency hiding. ------- */
#define NQKVG 384
#define NCAST 144
#define NPAIR 3072
__global__ __launch_bounds__(256,4) void k_pair_qkvg(
    const float* __restrict__ pair,
    const float* __restrict__ g_z,
    const float* __restrict__ b_z,
    const float* __restrict__ Wb,
    float* __restrict__ bias,
    const float* __restrict__ single,
    const float* __restrict__ g_s,
    const float* __restrict__ b_s,
    const float* __restrict__ Wq, const float* __restrict__ Wk,
    const float* __restrict__ Wv, const float* __restrict__ Wg,
    const float* __restrict__ Wo,
    const float* __restrict__ bg,
    u16* __restrict__ Wbf_o,
    u16* __restrict__ qb, u16* __restrict__ kb,
    u16* __restrict__ vT, float* __restrict__ gate){
  const int t = threadIdx.x;
  const int lane = t & 63;

  __shared__ u16 lds_s[48][384];   /* LN(single) tile, 36 KB; qkvg path only */

  if(blockIdx.x < NQKVG){
    /* ---- qkvg path: bx = blk%16 (48-row m-tile), by = blk/16 (which*6+ntile) ---- */
    const int blk = blockIdx.x;
    const int w = t >> 6, ln = lane & 15, quad = lane >> 4;
    if(w == 3) return;                      /* 3 active waves of 16 rows each */
    const int bx = blk % 16, by = blk / 16;
    const int m0 = bx*48 + w*16;
    const int which = by / 6;
    const int n0 = (by % 6)*64;
    const float* Wf = (which==0)?Wq:(which==1)?Wk:(which==2)?Wv:Wg;

    /* LN(single) for this wave's 16 rows -> LDS (wave-local: no barrier).
       Bit-identical to the original k_prep path (same ops, same order). */
#pragma unroll 1
    for(int rr=0; rr<16; rr++){
      const int gi = m0 + rr;
      const float* row = single + (size_t)gi*CS;
      float x[6];
      float sum = 0.f;
#pragma unroll
      for(int e=0;e<6;e++){ x[e] = row[lane + 64*e]; sum += x[e]; }
#pragma unroll
      for(int m=32;m>=1;m>>=1) sum += __shfl_xor(sum, m, 64);
      const float mu = sum * (1.f/CS);
      float vs = 0.f;
#pragma unroll
      for(int e=0;e<6;e++){ float d = x[e]-mu; vs += d*d; }
#pragma unroll
      for(int m=32;m>=1;m>>=1) vs += __shfl_xor(vs, m, 64);
      const float rs = rsqrtf(vs*(1.f/CS) + EPS);
#pragma unroll
      for(int e=0;e<6;e++){
        int c = lane + 64*e;
        lds_s[w*16 + rr][c] = f2bf_s((x[e]-mu)*rs*g_s[c] + b_s[c]);
      }
    }

    const u16* arow = &lds_s[w*16 + ln][quad*8];
    const float* browf = Wf + (size_t)(n0+ln)*CS + quad*8;

    f32x4 acc[4];
#pragma unroll
    for(int nb=0;nb<4;nb++) acc[nb] = (f32x4){0.f,0.f,0.f,0.f};

#pragma unroll 2
    for(int k0=0;k0<CS;k0+=32){
      bf16x8 a = *(const bf16x8*)(arow + k0);
#pragma unroll
      for(int nb=0;nb<4;nb++){
        const float* bp = browf + (size_t)nb*16*CS + k0;
        const float4 u0 = *(const float4*)(bp);
        const float4 u1 = *(const float4*)(bp + 4);
        bf16x8 bb;
        bb[0] = (short)f2bf_s(u0.x); bb[1] = (short)f2bf_s(u0.y);
        bb[2] = (short)f2bf_s(u0.z); bb[3] = (short)f2bf_s(u0.w);
        bb[4] = (short)f2bf_s(u1.x); bb[5] = (short)f2bf_s(u1.y);
        bb[6] = (short)f2bf_s(u1.z); bb[7] = (short)f2bf_s(u1.w);
        acc[nb] = __builtin_amdgcn_mfma_f32_16x16x32_bf16(a, bb, acc[nb], 0,0,0);
      }
    }

    if(which == 2){           /* v -> transposed bf16, 8B stores */
#pragma unroll
      for(int nb=0;nb<4;nb++){
        const int col = n0 + nb*16 + ln;
        ushort4 sv;
        sv.x = f2bf_s(acc[nb][0]); sv.y = f2bf_s(acc[nb][1]);
        sv.z = f2bf_s(acc[nb][2]); sv.w = f2bf_s(acc[nb][3]);
        *(ushort4*)(vT + (size_t)col*LSEQ + m0 + quad*4) = sv;
      }
    } else {
#pragma unroll
      for(int nb=0;nb<4;nb++){
#pragma unroll
        for(int r=0;r<4;r++){
          const int row = m0 + quad*4 + r;
          const int col = n0 + nb*16 + ln;
          const float val = acc[nb][r];
          if(which==0)      qb[row*CS+col] = f2bf_s(val*QK_SCALE);
          else if(which==1) kb[row*CS+col] = f2bf_s(val);
          else              gate[row*CS+col] = 1.f/(1.f + __expf(-(val + bg[col])));
        }
      }
    }
    return;
  }

  if(blockIdx.x < NQKVG + NCAST){
    /* ---- Wo cast path: 144 blocks x 256 threads x float4 = 147456 elems ---- */
    const int idx = (blockIdx.x - NQKVG)*256 + t;   /* < 36864 */
    const int off = idx*4;
    const float4 u = *(const float4*)(Wo + off);
    ushort4 o;
    o.x = f2bf_s(u.x); o.y = f2bf_s(u.y); o.z = f2bf_s(u.z); o.w = f2bf_s(u.w);
    *(ushort4*)(Wbf_o + off) = o;
    return;
  }

  /* ---- pair_bias path (unchanged body) ---- */
  const int wave = t >> 6;
  const int sub  = lane >> 4;
  const int lg   = lane & 15;
  const int z0   = lg*8;

  float wb_r[64], gz[8], bz[8];
#pragma unroll
  for(int zz=0; zz<8; zz++){
    gz[zz] = g_z[z0+zz];
    bz[zz] = b_z[z0+zz];
#pragma unroll
    for(int h=0; h<NH; h++) wb_r[zz*8+h] = Wb[(z0+zz)*NH + h];
  }
  const int hmap = 4*(lg&1) + (lg&2) + ((lg>>2)&1);

  const int ngroups = LL/16;
  for(int gidx = blockIdx.x - (NQKVG+NCAST); gidx < ngroups; gidx += NPAIR){
    const int r = gidx*16 + wave*4 + sub;
    const float4 u0 = *(const float4*)(pair + (size_t)r*CZ + z0);
    const float4 u1 = *(const float4*)(pair + (size_t)r*CZ + z0 + 4);
    float x[8] = {u0.x,u0.y,u0.z,u0.w,u1.x,u1.y,u1.z,u1.w};
    float sum=0.f, sq=0.f;
#pragma unroll
    for(int e=0;e<8;e++){ sum += x[e]; sq += x[e]*x[e]; }
#pragma unroll
    for(int m=1;m<16;m<<=1){ sum += __shfl_xor(sum,m,64); sq += __shfl_xor(sq,m,64); }
    const float mu = sum*(1.f/CZ);
    const float rs = rsqrtf(sq*(1.f/CZ) - mu*mu + EPS);
    float acc[8];
#pragma unroll
    for(int h=0;h<8;h++) acc[h]=0.f;
#pragma unroll
    for(int e=0;e<8;e++){
      const float zn = (x[e]-mu)*rs*gz[e] + bz[e];
#pragma unroll
      for(int h=0;h<8;h++) acc[h] += zn*wb_r[e*8+h];
    }
    float k1[4];
    {
      const bool hi = lg & 1;
#pragma unroll
      for(int j=0;j<4;j++){
        float send = hi ? acc[j] : acc[j+4];
        float recv = __shfl_xor(send, 1, 64);
        k1[j] = (hi ? acc[j+4] : acc[j]) + recv;
      }
    }
    float k2[2];
    {
      const bool hi = lg & 2;
#pragma unroll
      for(int j=0;j<2;j++){
        float send = hi ? k1[j] : k1[j+2];
        float recv = __shfl_xor(send, 2, 64);
        k2[j] = (hi ? k1[j+2] : k1[j]) + recv;
      }
    }
    float k3;
    {
      const bool hi = lg & 4;
      float send = hi ? k2[0] : k2[1];
      float recv = __shfl_xor(send, 4, 64);
      k3 = (hi ? k2[1] : k2[0]) + recv;
    }
    k3 += __shfl_xor(k3, 8, 64);
    if(lg < 8) bias[(size_t)hmap*LL + r] = k3;
  }
}

/* ---------- 2. fused flash attention (bf16 frags via vector loads) ---------- */
__global__ __launch_bounds__(256) void k_flash(
    const u16* __restrict__ qb, const u16* __restrict__ kb,
    const u16* __restrict__ vT, const float* __restrict__ bias,
    u16* __restrict__ attno_bf){
  const int h  = blockIdx.y;
  const int i0 = blockIdx.x * 16;
  const int t  = threadIdx.x;
  const int w    = t >> 6;
  const int lane = t & 63;
  const int ln   = lane & 15;
  const int quad = lane >> 4;

  __shared__ u16  S_lds[4][16][32];
  __shared__ float O_lds[4][16][48];
  __shared__ float ml_lds[4][2][16];

  const bf16x8 zf = {0,0,0,0,0,0,0,0};

  bf16x8 aq0, aq1;
  {
    const u16* qrow = qb + (size_t)(i0 + ln)*CS + h*HD;
    aq0 = *(const bf16x8*)(qrow + quad*8);
    aq1 = (quad < 2) ? *(const bf16x8*)(qrow + 32 + quad*8) : zf;
  }

  float m_r[4], l_r[4];
  f32x4 o[3];
#pragma unroll
  for(int r=0;r<4;r++){ m_r[r] = -INFINITY; l_r[r] = 0.f; }
#pragma unroll
  for(int db=0;db<3;db++) o[db] = (f32x4){0.f,0.f,0.f,0.f};

  for(int jt=0; jt<6; jt++){
    const int j0 = w*192 + jt*32;
    f32x4 s_f[2];
#pragma unroll
    for(int jb=0;jb<2;jb++){
      const u16* krow = kb + (size_t)(j0 + jb*16 + ln)*CS + h*HD;
      bf16x8 bk0 = *(const bf16x8*)(krow + quad*8);
      bf16x8 bk1 = (quad < 2) ? *(const bf16x8*)(krow + 32 + quad*8) : zf;
      f32x4 acc = (f32x4){0.f,0.f,0.f,0.f};
      acc = __builtin_amdgcn_mfma_f32_16x16x32_bf16(aq0, bk0, acc, 0,0,0);
      acc = __builtin_amdgcn_mfma_f32_16x16x32_bf16(aq1, bk1, acc, 0,0,0);
      s_f[jb] = acc;
    }
    float sv[2][4];
#pragma unroll
    for(int jb=0;jb<2;jb++)
#pragma unroll
      for(int r=0;r<4;r++)
        sv[jb][r] = s_f[jb][r] +
          bias[(size_t)h*LL + (size_t)(i0 + quad*4 + r)*LSEQ + j0 + jb*16 + ln];
    float tmax[4];
#pragma unroll
    for(int r=0;r<4;r++) tmax[r] = fmaxf(sv[0][r], sv[1][r]);
#pragma unroll
    for(int r=0;r<4;r++)
#pragma unroll
      for(int m=1;m<16;m<<=1) tmax[r] = fmaxf(tmax[r], __shfl_xor(tmax[r], m, 64));
    float alpha[4];
#pragma unroll
    for(int r=0;r<4;r++){
      const float mn = fmaxf(m_r[r], tmax[r]);
      alpha[r] = __expf(m_r[r] - mn);
      m_r[r] = mn;
    }
    float p[2][4], tsum[4];
#pragma unroll
    for(int r=0;r<4;r++){
      p[0][r] = __expf(sv[0][r] - m_r[r]);
      p[1][r] = __expf(sv[1][r] - m_r[r]);
      tsum[r] = p[0][r] + p[1][r];
    }
#pragma unroll
    for(int r=0;r<4;r++)
#pragma unroll
      for(int m=1;m<16;m<<=1) tsum[r] += __shfl_xor(tsum[r], m, 64);
#pragma unroll
    for(int r=0;r<4;r++) l_r[r] = l_r[r]*alpha[r] + tsum[r];
#pragma unroll
    for(int db=0;db<3;db++)
#pragma unroll
      for(int r=0;r<4;r++) o[db][r] *= alpha[r];
#pragma unroll
    for(int jb=0;jb<2;jb++)
#pragma unroll
      for(int r=0;r<4;r++) S_lds[w][quad*4+r][jb*16+ln] = f2bf_s(p[jb][r]);
    bf16x8 ap = *(const bf16x8*)&S_lds[w][ln][quad*8];
#pragma unroll
    for(int db=0;db<3;db++){
      bf16x8 bv = *(const bf16x8*)(vT + (size_t)(h*HD + db*16 + ln)*LSEQ + j0 + quad*8);
      o[db] = __builtin_amdgcn_mfma_f32_16x16x32_bf16(ap, bv, o[db], 0,0,0);
    }
  }

#pragma unroll
  for(int db=0;db<3;db++)
#pragma unroll
    for(int r=0;r<4;r++) O_lds[w][quad*4+r][db*16+ln] = o[db][r];
  if(ln == 0){
#pragma unroll
    for(int r=0;r<4;r++){
      ml_lds[w][0][quad*4+r] = m_r[r];
      ml_lds[w][1][quad*4+r] = l_r[r];
    }
  }
  __syncthreads();
#pragma unroll
  for(int e=0;e<3;e++){
    const int idx = t + e*256;
    const int row = idx / 48, d = idx % 48;
    float M = ml_lds[0][0][row];
#pragma unroll
    for(int ww=1;ww<4;ww++) M = fmaxf(M, ml_lds[ww][0][row]);
    float L = 0.f, O = 0.f;
#pragma unroll
    for(int ww=0;ww<4;ww++){
      const float f = __expf(ml_lds[ww][0][row] - M);
      L += ml_lds[ww][1][row] * f;
      O += O_lds[ww][row][d] * f;
    }
    attno_bf[(size_t)(i0+row)*CS + h*HD + d] = f2bf_s(O / L);
  }
}

/* ---- 3. MFMA GEMM: out = single + gate * (attno_bf @ Wo^T + bo) ---- */
__global__ __launch_bounds__(256) void k_final(
    const u16* __restrict__ attno_bf, const u16* __restrict__ Wo_bf,
    const float* __restrict__ bo, const float* __restrict__ single,
    const float* __restrict__ gate, float* __restrict__ out){
  const int t = threadIdx.x;
  const int w = t >> 6, lane = t & 63, ln = lane & 15, quad = lane >> 4;
  const int m0 = blockIdx.x*64 + w*16;
  const int n0 = blockIdx.y*64;

  const u16* arow = attno_bf + (size_t)(m0+ln)*CS + quad*8;
  const u16* brow = Wo_bf + (size_t)(n0+ln)*CS + quad*8;

  f32x4 acc[4];
#pragma unroll
  for(int nb=0;nb<4;nb++) acc[nb] = (f32x4){0.f,0.f,0.f,0.f};

#pragma unroll 4
  for(int k0=0;k0<CS;k0+=32){
    bf16x8 a = *(const bf16x8*)(arow + k0);
#pragma unroll
    for(int nb=0;nb<4;nb++){
      bf16x8 bb = *(const bf16x8*)(brow + (size_t)nb*16*CS + k0);
      acc[nb] = __builtin_amdgcn_mfma_f32_16x16x32_bf16(a, bb, acc[nb], 0,0,0);
    }
  }
#pragma unroll
  for(int nb=0;nb<4;nb++){
#pragma unroll
    for(int r=0;r<4;r++){
      const int row = m0 + quad*4 + r;
      const int col = n0 + nb*16 + ln;
      const float val = acc[nb][r] + bo[col];
      out[row*CS+col] = single[row*CS+col] + gate[row*CS+col]*val;
    }
  }
}

extern "C" void kernel_launch(void* const* d_in, const int* in_sizes, int n_in,
                              void* d_out, int out_size, void* d_ws, size_t ws_size,
                              hipStream_t stream){
  (void)in_sizes; (void)n_in; (void)out_size; (void)ws_size;
  const float* single = (const float*)d_in[0];
  const float* pair   = (const float*)d_in[1];
  const float* g_s    = (const float*)d_in[2];
  const float* b_s    = (const float*)d_in[3];
  const float* g_z    = (const float*)d_in[4];
  const float* b_z    = (const float*)d_in[5];
  const float* Wq     = (const float*)d_in[6];
  const float* Wk     = (const float*)d_in[7];
  const float* Wv     = (const float*)d_in[8];
  const float* Wb     = (const float*)d_in[9];
  const float* Wo     = (const float*)d_in[10];
  const float* bo     = (const float*)d_in[11];
  const float* Wg     = (const float*)d_in[12];
  const float* bg     = (const float*)d_in[13];
  float* out = (float*)d_out;

  float* ws     = (float*)d_ws;
  float* bias   = ws;                       /* [8][768][768] f32 */
  float* gate   = ws + 4718592;             /* [768][384] f32    */
  u16*   s_bf   = (u16*)(gate + 294912);    /* (unused now)      */
  u16*   qb     = s_bf + 294912;            /* [768][384] bf16   */
  u16*   kb     = qb + 294912;              /* [768][384] bf16   */
  u16*   vT     = kb + 294912;              /* [384][768] bf16   */
  u16*   attno  = vT + 294912;              /* [768][384] bf16   */
  u16*   Wbf    = attno + 294912;           /* slot 4 = Wo bf16  */
  u16*   Wbf_o  = Wbf + (size_t)4*WELEM;

  hipLaunchKernelGGL(k_pair_qkvg, dim3(NQKVG+NCAST+NPAIR), dim3(256), 0, stream,
                     pair, g_z, b_z, Wb, bias,
                     single, g_s, b_s, Wq, Wk, Wv, Wg, Wo, bg,
                     Wbf_o, qb, kb, vT, gate);
  hipLaunchKernelGGL(k_flash,     dim3(48,8),       dim3(256), 0, stream, qb, kb, vT, bias, attno);
  hipLaunchKernelGGL(k_final,     dim3(12,6),       dim3(256), 0, stream,
                     attno, Wbf_o, bo, single, gate, out);
}